// Round 1
// baseline (714.690 us; speedup 1.0000x reference)
//
#include <hip/hip_runtime.h>
#include <stdint.h>

#define S 2048
#define D 64
#define QTILE 64
#define KTILE 64
#define NKT (S / KTILE)

typedef short bf16x8 __attribute__((ext_vector_type(8)));
typedef float f32x4 __attribute__((ext_vector_type(4)));

// LDS row strides (in shorts)
#define KSTR 72   // K tile [key][d], +8 pad keeps 16B alignment for b128 frag reads
#define VSTR 66   // V^T tile [d][key], odd-ish stride to spread transpose-write banks
#define PSTR 72   // per-wave P tile [q][key]

__device__ __forceinline__ short f2bf(float f) {
    // round-to-nearest-even fp32 -> bf16 (bit pattern in a short)
    unsigned u = __float_as_uint(f);
    u = (u + 0x7FFFu + ((u >> 16) & 1u)) >> 16;
    return (short)u;
}

__global__ __launch_bounds__(256, 4) void sdpa_kernel(
    const float* __restrict__ Qg, const float* __restrict__ Kg,
    const float* __restrict__ Vg, float* __restrict__ out_ctx,
    float* __restrict__ out_attn)
{
    __shared__ short K_lds[KTILE * KSTR];       // 9216 B
    __shared__ short Vt_lds[D * VSTR];          // 8448 B
    __shared__ short p_lds[4 * 16 * PSTR];      // 9216 B (per-wave 16-row slices)

    const int tid  = threadIdx.x;
    const int wave = tid >> 6;
    const int lane = tid & 63;
    const int quad = lane >> 4;
    const int c    = lane & 15;

    const int bh = blockIdx.x >> 5;   // 32 q-tiles per head
    const int qt = blockIdx.x & 31;

    const float* Qh = Qg + (size_t)bh * S * D;
    const float* Kh = Kg + (size_t)bh * S * D;
    const float* Vh = Vg + (size_t)bh * S * D;
    float* attn_h = out_attn + (size_t)bh * S * S;

    const int q0 = qt * QTILE + wave * 16;   // this wave's first query row

    // ---- Q A-fragments (held in registers for both passes), pre-scaled by 1/sqrt(64) ----
    // A[m][k]: m = lane&15, k = quad*8 + j  (k-slices ks=0,1 cover d=0..63)
    bf16x8 qfrag[2];
    {
        const float* qp = Qh + (size_t)(q0 + c) * D + quad * 8;
        #pragma unroll
        for (int ks = 0; ks < 2; ++ks)
            #pragma unroll
            for (int j = 0; j < 8; ++j)
                qfrag[ks][j] = f2bf(qp[ks * 32 + j] * 0.125f);
    }

    float m_r[4], l_r[4];
    #pragma unroll
    for (int r = 0; r < 4; ++r) { m_r[r] = -1e30f; l_r[r] = 0.0f; }

    // =================== pass A: online row-max + sum-exp ===================
    for (int kt = 0; kt < NKT; ++kt) {
        {   // cooperative K-tile -> LDS (bf16): thread t loads 16 consecutive floats of one key row
            const int row = tid >> 2;
            const int dst = (tid & 3) * 16;
            const float* src = Kh + (size_t)(kt * KTILE + row) * D + dst;
            bf16x8 a, b;
            #pragma unroll
            for (int j = 0; j < 8; ++j) { a[j] = f2bf(src[j]); b[j] = f2bf(src[8 + j]); }
            *(bf16x8*)&K_lds[row * KSTR + dst] = a;
            *(bf16x8*)&K_lds[row * KSTR + dst + 8] = b;
        }
        __syncthreads();

        // scores: wave computes 16 q-rows x 64 keys, 4 n-blocks x 2 k-slice MFMAs
        f32x4 sacc[4];
        #pragma unroll
        for (int nb = 0; nb < 4; ++nb) {
            f32x4 z = {0.f, 0.f, 0.f, 0.f};
            sacc[nb] = z;
            #pragma unroll
            for (int ks = 0; ks < 2; ++ks) {
                // B[k][n]: n = lane&15 (key), k = quad*8+j (d)
                bf16x8 kf = *(const bf16x8*)&K_lds[(nb * 16 + c) * KSTR + ks * 32 + quad * 8];
                sacc[nb] = __builtin_amdgcn_mfma_f32_16x16x32_bf16(qfrag[ks], kf, sacc[nb], 0, 0, 0);
            }
        }
        // C layout: col=lane&15, row=quad*4+reg. Reduce across the 16 lanes of each quad-group.
        #pragma unroll
        for (int r = 0; r < 4; ++r) {
            float mx = fmaxf(fmaxf(sacc[0][r], sacc[1][r]), fmaxf(sacc[2][r], sacc[3][r]));
            #pragma unroll
            for (int off = 1; off < 16; off <<= 1)
                mx = fmaxf(mx, __shfl_xor(mx, off));
            const float mnew = fmaxf(m_r[r], mx);
            float t = __expf(sacc[0][r] - mnew) + __expf(sacc[1][r] - mnew)
                    + __expf(sacc[2][r] - mnew) + __expf(sacc[3][r] - mnew);
            #pragma unroll
            for (int off = 1; off < 16; off <<= 1)
                t += __shfl_xor(t, off);
            l_r[r] = l_r[r] * __expf(m_r[r] - mnew) + t;
            m_r[r] = mnew;
        }
        __syncthreads();
    }

    float inv_l[4];
    #pragma unroll
    for (int r = 0; r < 4; ++r) inv_l[r] = 1.0f / l_r[r];

    f32x4 cacc[4];
    #pragma unroll
    for (int nb = 0; nb < 4; ++nb) { f32x4 z = {0.f, 0.f, 0.f, 0.f}; cacc[nb] = z; }

    // =================== pass B: emit attn + accumulate P·V ===================
    for (int kt = 0; kt < NKT; ++kt) {
        {   // K tile (same as pass A)
            const int row = tid >> 2;
            const int dst = (tid & 3) * 16;
            const float* src = Kh + (size_t)(kt * KTILE + row) * D + dst;
            bf16x8 a, b;
            #pragma unroll
            for (int j = 0; j < 8; ++j) { a[j] = f2bf(src[j]); b[j] = f2bf(src[8 + j]); }
            *(bf16x8*)&K_lds[row * KSTR + dst] = a;
            *(bf16x8*)&K_lds[row * KSTR + dst + 8] = b;
        }
        {   // V tile transposed into Vt_lds[d][key]; global read is one full row per instr (coalesced)
            const int rbase = wave * 16;
            #pragma unroll
            for (int i = 0; i < 16; ++i) {
                float v = Vh[(size_t)(kt * KTILE + rbase + i) * D + lane];
                Vt_lds[lane * VSTR + rbase + i] = f2bf(v);
            }
        }
        __syncthreads();

        f32x4 sacc[4];
        #pragma unroll
        for (int nb = 0; nb < 4; ++nb) {
            f32x4 z = {0.f, 0.f, 0.f, 0.f};
            sacc[nb] = z;
            #pragma unroll
            for (int ks = 0; ks < 2; ++ks) {
                bf16x8 kf = *(const bf16x8*)&K_lds[(nb * 16 + c) * KSTR + ks * 32 + quad * 8];
                sacc[nb] = __builtin_amdgcn_mfma_f32_16x16x32_bf16(qfrag[ks], kf, sacc[nb], 0, 0, 0);
            }
        }

        // normalized probabilities: emit to global attn (nontemporal) + stash bf16 copy in LDS
        short* pw = &p_lds[wave * 16 * PSTR];
        #pragma unroll
        for (int nb = 0; nb < 4; ++nb) {
            #pragma unroll
            for (int r = 0; r < 4; ++r) {
                const float p = __expf(sacc[nb][r] - m_r[r]) * inv_l[r];
                __builtin_nontemporal_store(p,
                    attn_h + (size_t)(q0 + quad * 4 + r) * S + (size_t)(kt * KTILE + nb * 16 + c));
                pw[(quad * 4 + r) * PSTR + nb * 16 + c] = f2bf(p);
            }
        }

        // P re-enters as A-operand: A[m][k], m = lane&15 (q row), k = quad*8+j (key)
        // (same-wave LDS RAW: DS unit processes a wave's LDS ops in order; compiler inserts lgkmcnt)
        bf16x8 pa[2];
        #pragma unroll
        for (int ks = 0; ks < 2; ++ks)
            pa[ks] = *(const bf16x8*)&p_lds[(wave * 16 + c) * PSTR + ks * 32 + quad * 8];

        #pragma unroll
        for (int nb = 0; nb < 4; ++nb) {
            #pragma unroll
            for (int ks = 0; ks < 2; ++ks) {
                // B[k][n]: n = d = nb*16+c, k = key = ks*32+quad*8+j -> contiguous in Vt row
                bf16x8 vf;
                const short* vb = &Vt_lds[(nb * 16 + c) * VSTR + ks * 32 + quad * 8];
                #pragma unroll
                for (int j = 0; j < 8; ++j) vf[j] = vb[j];
                cacc[nb] = __builtin_amdgcn_mfma_f32_16x16x32_bf16(pa[ks], vf, cacc[nb], 0, 0, 0);
            }
        }
        __syncthreads();
    }

    // ---- store context [B,H,S,D] ----
    #pragma unroll
    for (int nb = 0; nb < 4; ++nb)
        #pragma unroll
        for (int r = 0; r < 4; ++r)
            __builtin_nontemporal_store(cacc[nb][r],
                out_ctx + (size_t)bh * S * D + (size_t)(q0 + quad * 4 + r) * D + nb * 16 + c);
}

extern "C" void kernel_launch(void* const* d_in, const int* in_sizes, int n_in,
                              void* d_out, int out_size, void* d_ws, size_t ws_size,
                              hipStream_t stream) {
    const float* Q = (const float*)d_in[0];
    const float* K = (const float*)d_in[1];
    const float* V = (const float*)d_in[2];
    float* ctx  = (float*)d_out;
    float* attn = (float*)d_out + (size_t)2 * 16 * S * D;  // context first, then attn

    dim3 grid(32 * (S / QTILE));  // 32 heads * 32 q-tiles = 1024 blocks
    dim3 block(256);              // 4 waves; each wave owns 16 query rows
    hipLaunchKernelGGL(sdpa_kernel, grid, block, 0, stream, Q, K, V, ctx, attn);
}